// Round 1
// baseline (79.616 us; speedup 1.0000x reference)
//
#include <hip/hip_runtime.h>

// SplineConv, degree-1, kernel 5x5, B=8 N=4096 Fin=Fout=64, E=32768.
// out[e,o] = mask[e] * ( bias[o] + sum_f x[e,f] * ( root[f,o] + sum_{s=0..3} b_s * W[wi_s][f,o] ) )
// where (b_s, wi_s) are bilinear-interp coefficients/corners of coord[e]*4 in the 5x5 grid.

#define FIN 64
#define FOUT 64

__global__ __launch_bounds__(256) void spline_conv_kernel(
    const float* __restrict__ x,      // [E,64]
    const float* __restrict__ coord,  // [E,2]
    const float* __restrict__ mask,   // [E]
    const float* __restrict__ weight, // [25,64,64]
    const float* __restrict__ root,   // [64,64]
    const float* __restrict__ bias,   // [64]
    float* __restrict__ out,          // [E,64]
    int E)
{
    __shared__ __align__(16) float xs[4][FIN];
    const int wid  = threadIdx.x >> 6;   // wave in block (4 waves)
    const int lane = threadIdx.x & 63;   // output channel
    const int e = blockIdx.x * 4 + wid;
    if (e >= E) return;

    // stage x row for broadcast reads
    xs[wid][lane] = x[e * FIN + lane];

    // spline basis (degree 1, D=2, kernel 5, open): v = coord*4
    const float c0 = coord[e * 2 + 0];
    const float c1 = coord[e * 2 + 1];
    const float v0 = c0 * 4.0f, v1 = c1 * 4.0f;
    const float fl0 = floorf(v0), fl1 = floorf(v1);
    const float fr0 = v0 - fl0, fr1 = v1 - fl1;
    const int i0 = (int)fl0, i1 = (int)fl1;

    // s = k0 + 2*k1; basis[s] = (k0?fr0:1-fr0)*(k1?fr1:1-fr1)
    float bs0 = (1.0f - fr0) * (1.0f - fr1);
    float bs1 = fr0 * (1.0f - fr1);
    float bs2 = (1.0f - fr0) * fr1;
    float bs3 = fr0 * fr1;

    const int a0 = i0 % 5, a1 = (i0 + 1) % 5;
    const int b0 = i1 % 5, b1 = (i1 + 1) % 5;
    // wi = (i0+k0)%5 + 5*((i1+k1)%5), weight row stride 64*64=4096
    const float* wp0 = weight + (a0 + 5 * b0) * 4096 + lane;
    const float* wp1 = weight + (a1 + 5 * b0) * 4096 + lane;
    const float* wp2 = weight + (a0 + 5 * b1) * 4096 + lane;
    const float* wp3 = weight + (a1 + 5 * b1) * 4096 + lane;
    const float* rp  = root + lane;

    __syncthreads();
    const float* xrow = xs[wid];

    float acc = 0.0f;
    #pragma unroll 2
    for (int f4 = 0; f4 < FIN / 4; ++f4) {
        const float4 xf = *reinterpret_cast<const float4*>(xrow + f4 * 4);
        const int base = f4 * 4 * FOUT;
        float xj[4] = {xf.x, xf.y, xf.z, xf.w};
        #pragma unroll
        for (int j = 0; j < 4; ++j) {
            const int off = base + j * FOUT;
            const float w0 = wp0[off];
            const float w1 = wp1[off];
            const float w2 = wp2[off];
            const float w3 = wp3[off];
            const float r  = rp[off];
            float t = fmaf(bs3, w3, r);
            t = fmaf(bs2, w2, t);
            t = fmaf(bs1, w1, t);
            t = fmaf(bs0, w0, t);
            acc = fmaf(xj[j], t, acc);
        }
    }

    const float m = mask[e];
    out[e * FOUT + lane] = (acc + bias[lane]) * m;
}

extern "C" void kernel_launch(void* const* d_in, const int* in_sizes, int n_in,
                              void* d_out, int out_size, void* d_ws, size_t ws_size,
                              hipStream_t stream) {
    const float* x      = (const float*)d_in[0];  // [8,4096,64]
    const float* coord  = (const float*)d_in[1];  // [8,4096,2]
    const float* mask   = (const float*)d_in[2];  // [8,4096]
    const float* weight = (const float*)d_in[3];  // [25,64,64]
    const float* root   = (const float*)d_in[4];  // [64,64]
    const float* bias   = (const float*)d_in[5];  // [64]
    float* out = (float*)d_out;

    const int E = in_sizes[2];           // 32768 points
    const int blocks = (E + 3) / 4;      // 4 points (waves) per block

    spline_conv_kernel<<<blocks, 256, 0, stream>>>(x, coord, mask, weight, root, bias, out, E);
}

// Round 2
// 26.025 us; speedup vs baseline: 3.0593x; 3.0593x over previous
//
#include <hip/hip_runtime.h>

// SplineConv via cell-bucketed bf16 MFMA GEMM.
// out[e,:] = mask[e] * ( bias + x[e]·root + sum_{s=0..3} b_s[e] · x[e]·W[wi_s(e)] )
// Points bucketed by interpolation cell (<=25 cells); per 64-point tile of a cell,
// the 4 corner weight matrices + root are staged once in LDS (bf16, transposed,
// XOR-swizzled) and consumed by mfma_f32_16x16x32_bf16 with 5 accumulators;
// basis coefficients are applied per-row in the epilogue (keeps inner loop VALU-free).

typedef __attribute__((ext_vector_type(8))) short bhalf8;
typedef __attribute__((ext_vector_type(4))) float f32x4;

__device__ __forceinline__ unsigned short f2bf(float f) {
    unsigned int u = __builtin_bit_cast(unsigned int, f);
    u += 0x7fffu + ((u >> 16) & 1u);
    return (unsigned short)(u >> 16);
}

__global__ void k_zero(int* cnt) {
    if (threadIdx.x < 32) cnt[threadIdx.x] = 0;
}

__global__ __launch_bounds__(256) void k_prep(
    const float* __restrict__ coord, float4* __restrict__ basis4,
    int* __restrict__ cellA, int* __restrict__ posA, int* __restrict__ cnt, int E)
{
    __shared__ int lcnt[25], lbase[25];
    int tid = threadIdx.x;
    if (tid < 25) lcnt[tid] = 0;
    __syncthreads();
    int e = blockIdx.x * 256 + tid;
    int c = 0, lpos = 0;
    float4 b4 = make_float4(0.f, 0.f, 0.f, 0.f);
    if (e < E) {
        float c0 = coord[2 * e], c1 = coord[2 * e + 1];
        float v0 = c0 * 4.0f, v1 = c1 * 4.0f;
        float fl0 = floorf(v0), fl1 = floorf(v1);
        float f0 = v0 - fl0, f1 = v1 - fl1;
        int i0 = ((int)fl0) % 5, i1 = ((int)fl1) % 5;   // 0..4 (4 only at coord==1.0)
        c = i0 + 5 * i1;                                 // cell id 0..24
        b4.x = (1.f - f0) * (1.f - f1);
        b4.y = f0 * (1.f - f1);
        b4.z = (1.f - f0) * f1;
        b4.w = f0 * f1;
        lpos = atomicAdd(&lcnt[c], 1);
    }
    __syncthreads();
    if (tid < 25 && lcnt[tid] > 0) lbase[tid] = atomicAdd(&cnt[tid], lcnt[tid]);
    __syncthreads();
    if (e < E) {
        basis4[e] = b4;
        cellA[e] = c;
        posA[e] = lbase[c] + lpos;
    }
}

__global__ void k_scan(const int* __restrict__ cnt, int* __restrict__ off) {
    if (threadIdx.x == 0) {
        int a = 0;
        for (int c = 0; c < 25; ++c) { off[c] = a; a += cnt[c]; }
        off[25] = a;
    }
}

__global__ __launch_bounds__(256) void k_scatter(
    const int* __restrict__ cellA, const int* __restrict__ posA,
    const int* __restrict__ off, int* __restrict__ idx, int E)
{
    int e = blockIdx.x * 256 + threadIdx.x;
    if (e < E) idx[off[cellA[e]] + posA[e]] = e;
}

// Main: one block = one 64-point tile of one cell. 4 waves in 2x2 (wm, wn) grid:
// wave computes 32 points x 32 outputs as 2x2 fragments of 16x16x32 MFMA.
__global__ __launch_bounds__(256) void k_main(
    const float* __restrict__ x, const float* __restrict__ mask,
    const float* __restrict__ weight, const float* __restrict__ root,
    const float* __restrict__ bias, const float4* __restrict__ basis4,
    const int* __restrict__ off, const int* __restrict__ idx,
    float* __restrict__ out)
{
    // xs: [p=64][f=64] bf16, 16B-granule swizzled by (p&7)
    // wt: [s=5][o=64][f=64] bf16 (transposed), granule swizzled by (o&7)
    __shared__ __align__(16) unsigned short xs[64 * 64];
    __shared__ __align__(16) unsigned short wt[5 * 64 * 64];
    __shared__ float4 bsv[64];
    __shared__ float  msk[64];
    __shared__ int    eid[64];
    __shared__ float  bsh[64];

    // tile -> (cell, tile-within-cell)
    int tile = blockIdx.x;
    int c = -1, t = 0, accum = 0;
    for (int cc = 0; cc < 25; ++cc) {
        int n = off[cc + 1] - off[cc];
        int nt = (n + 63) >> 6;
        if (tile < accum + nt) { c = cc; t = tile - accum; break; }
        accum += nt;
    }
    if (c < 0) return;
    int base = off[c] + t * 64;
    int npts = off[c + 1] - off[c] - t * 64;
    if (npts > 64) npts = 64;

    int tid = threadIdx.x;

    // point metadata
    if (tid < 64) {
        bsh[tid] = bias[tid];
        if (tid < npts) {
            int e = idx[base + tid];
            eid[tid] = e;
            bsv[tid] = basis4[e];
            msk[tid] = mask[e];
        }
    }

    // stage gathered x rows -> bf16 LDS (thread: row p = tid>>2, two 8-elem granules)
    {
        int p = tid >> 2;
        if (p < npts) {
            int e = idx[base + p];
            const float4* xr = (const float4*)(x + (long)e * 64);
            int g0 = (tid & 3) * 2;
            #pragma unroll
            for (int gg = 0; gg < 2; ++gg) {
                int g = g0 + gg;
                float4 lo = xr[2 * g], hi = xr[2 * g + 1];
                bhalf8 u;
                u[0] = f2bf(lo.x); u[1] = f2bf(lo.y); u[2] = f2bf(lo.z); u[3] = f2bf(lo.w);
                u[4] = f2bf(hi.x); u[5] = f2bf(hi.y); u[6] = f2bf(hi.z); u[7] = f2bf(hi.w);
                *(bhalf8*)((char*)xs + p * 128 + ((g ^ (p & 7)) << 4)) = u;
            }
        }
    }

    // stage 4 corner weights + root, transposed to [o][f] bf16, swizzled.
    // thread: o = tid&63 (coalesced global reads along o), f-strip q = tid>>6.
    {
        int i0 = c % 5, i1 = c / 5;
        int a0 = i0, a1 = (i0 + 1) % 5, b0 = i1, b1 = (i1 + 1) % 5;
        const float* srcs[5] = {
            weight + (a0 + 5 * b0) * 4096,
            weight + (a1 + 5 * b0) * 4096,
            weight + (a0 + 5 * b1) * 4096,
            weight + (a1 + 5 * b1) * 4096,
            root
        };
        int o = tid & 63, q = tid >> 6;
        #pragma unroll
        for (int s = 0; s < 5; ++s) {
            const float* src = srcs[s];
            #pragma unroll
            for (int half = 0; half < 2; ++half) {
                int g = half * 4 + q;
                int f0v = g * 8;
                bhalf8 u;
                #pragma unroll
                for (int j = 0; j < 8; ++j) u[j] = f2bf(src[(f0v + j) * 64 + o]);
                *(bhalf8*)((char*)wt + s * 8192 + o * 128 + ((g ^ (o & 7)) << 4)) = u;
            }
        }
    }
    __syncthreads();

    int lane = tid & 63, wv = tid >> 6;
    int wm = wv >> 1, wn = wv & 1;
    int lr = lane & 15, lg = lane >> 4;

    f32x4 zero4 = {0.f, 0.f, 0.f, 0.f};
    f32x4 acc5[5][2][2];
    #pragma unroll
    for (int s = 0; s < 5; ++s)
        #pragma unroll
        for (int m = 0; m < 2; ++m)
            #pragma unroll
            for (int n = 0; n < 2; ++n) acc5[s][m][n] = zero4;

    #pragma unroll
    for (int kk = 0; kk < 2; ++kk) {
        bhalf8 a[2];
        #pragma unroll
        for (int m = 0; m < 2; ++m) {
            int p = wm * 32 + m * 16 + lr;
            int g = kk * 4 + lg;
            a[m] = *(const bhalf8*)((const char*)xs + p * 128 + ((g ^ (p & 7)) << 4));
        }
        #pragma unroll
        for (int s = 0; s < 5; ++s) {
            #pragma unroll
            for (int n = 0; n < 2; ++n) {
                int o = wn * 32 + n * 16 + lr;
                int g = kk * 4 + lg;
                bhalf8 b = *(const bhalf8*)((const char*)wt + s * 8192 + o * 128 + ((g ^ (o & 7)) << 4));
                #pragma unroll
                for (int m = 0; m < 2; ++m)
                    acc5[s][m][n] = __builtin_amdgcn_mfma_f32_16x16x32_bf16(a[m], b, acc5[s][m][n], 0, 0, 0);
            }
        }
    }

    // epilogue: out[row] = acc_root + sum_s b_s[row]*acc_s, + bias, * mask
    #pragma unroll
    for (int m = 0; m < 2; ++m) {
        #pragma unroll
        for (int n = 0; n < 2; ++n) {
            int col = wn * 32 + n * 16 + lr;
            int pb = wm * 32 + m * 16 + lg * 4;
            #pragma unroll
            for (int r = 0; r < 4; ++r) {
                int p = pb + r;
                if (p < npts) {
                    float4 b4 = bsv[p];
                    float v = acc5[4][m][n][r]
                            + b4.x * acc5[0][m][n][r]
                            + b4.y * acc5[1][m][n][r]
                            + b4.z * acc5[2][m][n][r]
                            + b4.w * acc5[3][m][n][r];
                    v = (v + bsh[col]) * msk[p];
                    out[(long)eid[p] * 64 + col] = v;
                }
            }
        }
    }
}

extern "C" void kernel_launch(void* const* d_in, const int* in_sizes, int n_in,
                              void* d_out, int out_size, void* d_ws, size_t ws_size,
                              hipStream_t stream) {
    const float* x      = (const float*)d_in[0];  // [8,4096,64]
    const float* coord  = (const float*)d_in[1];  // [8,4096,2]
    const float* mask   = (const float*)d_in[2];  // [8,4096]
    const float* weight = (const float*)d_in[3];  // [25,64,64]
    const float* root   = (const float*)d_in[4];  // [64,64]
    const float* bias   = (const float*)d_in[5];  // [64]
    float* out = (float*)d_out;

    const int E = in_sizes[2];  // 32768

    char* ws = (char*)d_ws;
    int*    cnt    = (int*)ws;                                  // 32 ints
    int*    off    = (int*)(ws + 128);                          // 32 ints
    float4* basis4 = (float4*)(ws + 256);                       // E float4
    int*    cellA  = (int*)(ws + 256 + (size_t)E * 16);
    int*    posA   = (int*)((char*)cellA + (size_t)E * 4);
    int*    idx    = (int*)((char*)posA + (size_t)E * 4);

    k_zero<<<1, 64, 0, stream>>>(cnt);
    k_prep<<<(E + 255) / 256, 256, 0, stream>>>(coord, basis4, cellA, posA, cnt, E);
    k_scan<<<1, 64, 0, stream>>>(cnt, off);
    k_scatter<<<(E + 255) / 256, 256, 0, stream>>>(cellA, posA, off, idx, E);

    int maxTiles = (E + 63) / 64 + 25;
    k_main<<<maxTiles, 256, 0, stream>>>(x, mask, weight, root, bias, basis4, off, idx, out);
}

// Round 3
// 23.883 us; speedup vs baseline: 3.3336x; 1.0897x over previous
//
#include <hip/hip_runtime.h>
#include <hip/hip_bf16.h>

// SplineConv via cell-bucketed bf16 MFMA GEMM — 3-dispatch version.
// out[e,:] = mask[e] * ( bias + x[e]·root + sum_{s=0..3} b_s[e] · x[e]·W[wi_s(e)] )
// prep: cell+basis per point, padded-bucket scatter (LDS histogram + global atomics).
// main: one block per 64-point tile of one cell; stage 4 corner W + root in LDS
// (bf16, transposed, XOR-swizzled), 5 accumulators of mfma_f32_16x16x32_bf16,
// basis applied in epilogue.

#define CAP 3072   // per-cell bucket capacity (E/16 expected ~2048, sigma ~45)

typedef __attribute__((ext_vector_type(8))) short bhalf8;
typedef __attribute__((ext_vector_type(4))) float f32x4;

__device__ __forceinline__ unsigned short f2bf(float f) {
    return __builtin_bit_cast(unsigned short, __float2bfloat16(f));
}

__global__ __launch_bounds__(256) void k_prep(
    const float* __restrict__ coord, float4* __restrict__ basis4,
    int* __restrict__ cnt, int* __restrict__ idx, int E)
{
    __shared__ int lcnt[25], lbase[25];
    int tid = threadIdx.x;
    if (tid < 25) lcnt[tid] = 0;
    __syncthreads();
    int e = blockIdx.x * 256 + tid;
    int c = 0, lpos = 0;
    float4 b4 = make_float4(0.f, 0.f, 0.f, 0.f);
    if (e < E) {
        float2 cc = *(const float2*)(coord + 2 * e);
        float v0 = cc.x * 4.0f, v1 = cc.y * 4.0f;
        float fl0 = floorf(v0), fl1 = floorf(v1);
        float f0 = v0 - fl0, f1 = v1 - fl1;
        int i0 = ((int)fl0) % 5, i1 = ((int)fl1) % 5;
        c = i0 + 5 * i1;
        b4.x = (1.f - f0) * (1.f - f1);
        b4.y = f0 * (1.f - f1);
        b4.z = (1.f - f0) * f1;
        b4.w = f0 * f1;
        lpos = atomicAdd(&lcnt[c], 1);
    }
    __syncthreads();
    if (tid < 25 && lcnt[tid] > 0) lbase[tid] = atomicAdd(&cnt[tid], lcnt[tid]);
    __syncthreads();
    if (e < E) {
        basis4[e] = b4;
        int pos = lbase[c] + lpos;
        if (pos < CAP) idx[c * CAP + pos] = e;
    }
}

// Main: one block = one 64-point tile of one cell. 4 waves in 2x2 (wm, wn) grid.
__global__ __launch_bounds__(256) void k_main(
    const float* __restrict__ x, const float* __restrict__ mask,
    const float* __restrict__ weight, const float* __restrict__ root,
    const float* __restrict__ bias, const float4* __restrict__ basis4,
    const int* __restrict__ cnt, const int* __restrict__ idx,
    float* __restrict__ out)
{
    __shared__ __align__(16) unsigned short xs[64 * 64];      // [p][f] swizzled
    __shared__ __align__(16) unsigned short wt[5 * 64 * 64];  // [s][o][f] swizzled
    __shared__ float4 bsv[64];
    __shared__ float  msk[64];
    __shared__ int    eid[64];
    __shared__ float  bsh[64];

    // tile -> (cell, tile-within-cell) from per-cell counts
    int tile = blockIdx.x;
    int c = -1, t = 0, accum = 0, ncell = 0;
    for (int cc = 0; cc < 25; ++cc) {
        int n = cnt[cc]; if (n > CAP) n = CAP;
        int nt = (n + 63) >> 6;
        if (c < 0 && tile < accum + nt) { c = cc; t = tile - accum; ncell = n; }
        accum += nt;
    }
    if (c < 0) return;
    int base = c * CAP + t * 64;
    int npts = ncell - t * 64;
    if (npts > 64) npts = 64;

    int tid = threadIdx.x;

    if (tid < 64) {
        bsh[tid] = bias[tid];
        if (tid < npts) {
            int e = idx[base + tid];
            eid[tid] = e;
            bsv[tid] = basis4[e];
            msk[tid] = mask[e];
        }
    }

    // stage gathered x rows -> bf16 LDS (thread: row p = tid>>2, two 8-elem granules)
    {
        int p = tid >> 2;
        if (p < npts) {
            int e = idx[base + p];
            const float4* xr = (const float4*)(x + (long)e * 64);
            int g0 = (tid & 3) * 2;
            #pragma unroll
            for (int gg = 0; gg < 2; ++gg) {
                int g = g0 + gg;
                float4 lo = xr[2 * g], hi = xr[2 * g + 1];
                bhalf8 u;
                u[0] = f2bf(lo.x); u[1] = f2bf(lo.y); u[2] = f2bf(lo.z); u[3] = f2bf(lo.w);
                u[4] = f2bf(hi.x); u[5] = f2bf(hi.y); u[6] = f2bf(hi.z); u[7] = f2bf(hi.w);
                *(bhalf8*)((char*)xs + p * 128 + ((g ^ (p & 7)) << 4)) = u;
            }
        }
    }

    // stage 4 corner weights + root, transposed to [o][f] bf16, swizzled
    {
        int i0 = c % 5, i1 = c / 5;
        int a0 = i0, a1 = (i0 + 1) % 5, b0 = i1, b1 = (i1 + 1) % 5;
        const float* srcs[5] = {
            weight + (a0 + 5 * b0) * 4096,
            weight + (a1 + 5 * b0) * 4096,
            weight + (a0 + 5 * b1) * 4096,
            weight + (a1 + 5 * b1) * 4096,
            root
        };
        int o = tid & 63, q = tid >> 6;
        #pragma unroll
        for (int s = 0; s < 5; ++s) {
            const float* src = srcs[s];
            #pragma unroll
            for (int half = 0; half < 2; ++half) {
                int g = half * 4 + q;
                int f0v = g * 8;
                bhalf8 u;
                #pragma unroll
                for (int j = 0; j < 8; ++j) u[j] = f2bf(src[(f0v + j) * 64 + o]);
                *(bhalf8*)((char*)wt + s * 8192 + o * 128 + ((g ^ (o & 7)) << 4)) = u;
            }
        }
    }
    __syncthreads();

    int lane = tid & 63, wv = tid >> 6;
    int wm = wv >> 1, wn = wv & 1;
    int lr = lane & 15, lg = lane >> 4;

    f32x4 zero4 = {0.f, 0.f, 0.f, 0.f};
    f32x4 acc5[5][2][2];
    #pragma unroll
    for (int s = 0; s < 5; ++s)
        #pragma unroll
        for (int m = 0; m < 2; ++m)
            #pragma unroll
            for (int n = 0; n < 2; ++n) acc5[s][m][n] = zero4;

    #pragma unroll
    for (int kk = 0; kk < 2; ++kk) {
        bhalf8 a[2];
        #pragma unroll
        for (int m = 0; m < 2; ++m) {
            int p = wm * 32 + m * 16 + lr;
            int g = kk * 4 + lg;
            a[m] = *(const bhalf8*)((const char*)xs + p * 128 + ((g ^ (p & 7)) << 4));
        }
        #pragma unroll
        for (int s = 0; s < 5; ++s) {
            #pragma unroll
            for (int n = 0; n < 2; ++n) {
                int o = wn * 32 + n * 16 + lr;
                int g = kk * 4 + lg;
                bhalf8 b = *(const bhalf8*)((const char*)wt + s * 8192 + o * 128 + ((g ^ (o & 7)) << 4));
                #pragma unroll
                for (int m = 0; m < 2; ++m)
                    acc5[s][m][n] = __builtin_amdgcn_mfma_f32_16x16x32_bf16(a[m], b, acc5[s][m][n], 0, 0, 0);
            }
        }
    }

    #pragma unroll
    for (int m = 0; m < 2; ++m) {
        #pragma unroll
        for (int n = 0; n < 2; ++n) {
            int col = wn * 32 + n * 16 + lr;
            int pb = wm * 32 + m * 16 + lg * 4;
            #pragma unroll
            for (int r = 0; r < 4; ++r) {
                int p = pb + r;
                if (p < npts) {
                    float4 b4 = bsv[p];
                    float v = acc5[4][m][n][r]
                            + b4.x * acc5[0][m][n][r]
                            + b4.y * acc5[1][m][n][r]
                            + b4.z * acc5[2][m][n][r]
                            + b4.w * acc5[3][m][n][r];
                    v = (v + bsh[col]) * msk[p];
                    out[(long)eid[p] * 64 + col] = v;
                }
            }
        }
    }
}

extern "C" void kernel_launch(void* const* d_in, const int* in_sizes, int n_in,
                              void* d_out, int out_size, void* d_ws, size_t ws_size,
                              hipStream_t stream) {
    const float* x      = (const float*)d_in[0];  // [8,4096,64]
    const float* coord  = (const float*)d_in[1];  // [8,4096,2]
    const float* mask   = (const float*)d_in[2];  // [8,4096]
    const float* weight = (const float*)d_in[3];  // [25,64,64]
    const float* root   = (const float*)d_in[4];  // [64,64]
    const float* bias   = (const float*)d_in[5];  // [64]
    float* out = (float*)d_out;

    const int E = in_sizes[2];  // 32768

    char* ws = (char*)d_ws;
    int*    cnt    = (int*)ws;                       // 25 ints (pad to 128B)
    float4* basis4 = (float4*)(ws + 256);            // E float4
    int*    idx    = (int*)(ws + 256 + (size_t)E * 16);  // 25*CAP ints

    hipMemsetAsync(cnt, 0, 128, stream);
    k_prep<<<(E + 255) / 256, 256, 0, stream>>>(coord, basis4, cnt, idx, E);

    int maxTiles = (E + 63) / 64 + 25;
    k_main<<<maxTiles, 256, 0, stream>>>(x, mask, weight, root, bias, basis4, cnt, idx, out);
}

// Round 4
// 21.636 us; speedup vs baseline: 3.6799x; 1.1039x over previous
//
#include <hip/hip_runtime.h>
#include <hip/hip_bf16.h>

// SplineConv via cell-bucketed bf16 MFMA GEMM — 2-dispatch, deterministic buckets.
// out[e,:] = mask[e] * ( bias + x[e]·root + sum_{s=0..3} b_s[e] · x[e]·W[wi_s(e)] )
// prep: per-(cell, prep-block) padded buckets, LDS histogram only (no global
//       atomics, no zeroed memory -> no memset dispatch).
// main: per 64-point tile of a cell: reconstruct totals + scan bucket counts,
//       gather point ids, stage x + 4 corner W + root in LDS (bf16, transposed,
//       XOR-swizzled), 5 accumulators of mfma_f32_16x16x32_bf16, basis in epilogue.

#define NCELL 25
#define NPREP 128     // prep blocks, 256 points each (E = 32768)
#define CAP_B 64      // per-(cell,block) bucket capacity; mean fill 16, sigma 3.9

typedef __attribute__((ext_vector_type(8))) short bhalf8;
typedef __attribute__((ext_vector_type(4))) float f32x4;

__device__ __forceinline__ unsigned short f2bf(float f) {
    return __builtin_bit_cast(unsigned short, __float2bfloat16(f));
}

__global__ __launch_bounds__(256) void k_prep(
    const float* __restrict__ coord, float4* __restrict__ basis4,
    int* __restrict__ cnt2, int* __restrict__ idx2, int E)
{
    __shared__ int lcnt[NCELL];
    int tid = threadIdx.x, blk = blockIdx.x;
    if (tid < NCELL) lcnt[tid] = 0;
    __syncthreads();
    int e = blk * 256 + tid;
    int c = 0, lpos = 0;
    float4 b4 = make_float4(0.f, 0.f, 0.f, 0.f);
    if (e < E) {
        float2 cc = *(const float2*)(coord + 2 * e);
        float v0 = cc.x * 4.0f, v1 = cc.y * 4.0f;
        float fl0 = floorf(v0), fl1 = floorf(v1);
        float f0 = v0 - fl0, f1 = v1 - fl1;
        int i0 = ((int)fl0) % 5, i1 = ((int)fl1) % 5;
        c = i0 + 5 * i1;
        b4.x = (1.f - f0) * (1.f - f1);
        b4.y = f0 * (1.f - f1);
        b4.z = (1.f - f0) * f1;
        b4.w = f0 * f1;
        lpos = atomicAdd(&lcnt[c], 1);
    }
    __syncthreads();
    if (e < E) {
        basis4[e] = b4;
        if (lpos < CAP_B) idx2[(c * NPREP + blk) * CAP_B + lpos] = e;
    }
    if (tid < NCELL) {
        int v = lcnt[tid];
        cnt2[tid * NPREP + blk] = v < CAP_B ? v : CAP_B;
    }
}

// Main: one block = one 64-point tile of one cell. 4 waves in 2x2 (wm, wn) grid.
__global__ __launch_bounds__(256) void k_main(
    const float* __restrict__ x, const float* __restrict__ mask,
    const float* __restrict__ weight, const float* __restrict__ root,
    const float* __restrict__ bias, const float4* __restrict__ basis4,
    const int* __restrict__ cnt2, const int* __restrict__ idx2,
    float* __restrict__ out)
{
    __shared__ __align__(16) unsigned short xs[64 * 64];      // [p][f] swizzled
    __shared__ __align__(16) unsigned short wt[5 * 64 * 64];  // [s][o][f] swizzled
    __shared__ float4 bsv[64];
    __shared__ float  msk[64];
    __shared__ int    eid[64];
    __shared__ float  bsh[64];
    __shared__ int    stot[NCELL];
    __shared__ int    sprefix[NPREP + 1];

    int tid = threadIdx.x;

    // --- per-cell totals from cnt2 (25 cells x 8 partials of 16) ---
    if (tid < NCELL) stot[tid] = 0;
    __syncthreads();
    if (tid < NCELL * 8) {
        int c = tid >> 3, part = tid & 7;
        const int* p = cnt2 + c * NPREP + part * 16;
        int s = 0;
        #pragma unroll
        for (int i = 0; i < 16; ++i) s += p[i];
        atomicAdd(&stot[c], s);
    }
    __syncthreads();

    // --- tile -> (cell, tile-within-cell) ---
    int tile = blockIdx.x;
    int c = -1, t = 0, accum = 0, ncell = 0;
    for (int cc = 0; cc < NCELL; ++cc) {
        int n = stot[cc];
        int nt = (n + 63) >> 6;
        if (c < 0 && tile < accum + nt) { c = cc; t = tile - accum; ncell = n; }
        accum += nt;
    }
    if (c < 0) return;
    int npts = ncell - t * 64;
    if (npts > 64) npts = 64;

    // --- exclusive prefix of cnt2[c][0..127] into sprefix ---
    {
        int v = 0;
        if (tid < NPREP) v = cnt2[c * NPREP + tid];
        int lane = tid & 63;
        int s = v;
        #pragma unroll
        for (int d = 1; d < 64; d <<= 1) {
            int u = __shfl_up(s, d, 64);
            if (lane >= d) s += u;
        }
        if (tid < NPREP) sprefix[tid + 1] = s;   // inclusive -> shifted
        if (tid == 0) sprefix[0] = 0;
        __syncthreads();
        int w0 = sprefix[64];
        if (tid >= 64 && tid < NPREP) sprefix[tid + 1] += w0;
        __syncthreads();
    }

    // --- gather 64 point ids + metadata ---
    if (tid < 64) {
        bsh[tid] = bias[tid];
        if (tid < npts) {
            int gpos = t * 64 + tid;
            int lo = 0, hi = NPREP;   // sprefix[lo] <= gpos < sprefix[hi]
            while (hi - lo > 1) {
                int mid = (lo + hi) >> 1;
                if (sprefix[mid] <= gpos) lo = mid; else hi = mid;
            }
            int e = idx2[(c * NPREP + lo) * CAP_B + (gpos - sprefix[lo])];
            eid[tid] = e;
            bsv[tid] = basis4[e];
            msk[tid] = mask[e];
        }
    }
    __syncthreads();   // eid ready

    // --- stage gathered x rows -> bf16 LDS ---
    {
        int p = tid >> 2;
        if (p < npts) {
            int e = eid[p];
            const float4* xr = (const float4*)(x + (long)e * 64);
            int g0 = (tid & 3) * 2;
            #pragma unroll
            for (int gg = 0; gg < 2; ++gg) {
                int g = g0 + gg;
                float4 lo = xr[2 * g], hi = xr[2 * g + 1];
                bhalf8 u;
                u[0] = f2bf(lo.x); u[1] = f2bf(lo.y); u[2] = f2bf(lo.z); u[3] = f2bf(lo.w);
                u[4] = f2bf(hi.x); u[5] = f2bf(hi.y); u[6] = f2bf(hi.z); u[7] = f2bf(hi.w);
                *(bhalf8*)((char*)xs + p * 128 + ((g ^ (p & 7)) << 4)) = u;
            }
        }
    }

    // --- stage 4 corner weights + root, transposed to [o][f] bf16, swizzled ---
    {
        int i0 = c % 5, i1 = c / 5;
        int a0 = i0, a1 = (i0 + 1) % 5, b0 = i1, b1 = (i1 + 1) % 5;
        const float* srcs[5] = {
            weight + (a0 + 5 * b0) * 4096,
            weight + (a1 + 5 * b0) * 4096,
            weight + (a0 + 5 * b1) * 4096,
            weight + (a1 + 5 * b1) * 4096,
            root
        };
        int o = tid & 63, q = tid >> 6;
        #pragma unroll
        for (int s = 0; s < 5; ++s) {
            const float* src = srcs[s];
            #pragma unroll
            for (int half = 0; half < 2; ++half) {
                int g = half * 4 + q;
                int f0v = g * 8;
                bhalf8 u;
                #pragma unroll
                for (int j = 0; j < 8; ++j) u[j] = f2bf(src[(f0v + j) * 64 + o]);
                *(bhalf8*)((char*)wt + s * 8192 + o * 128 + ((g ^ (o & 7)) << 4)) = u;
            }
        }
    }
    __syncthreads();

    int lane = tid & 63, wv = tid >> 6;
    int wm = wv >> 1, wn = wv & 1;
    int lr = lane & 15, lg = lane >> 4;

    f32x4 zero4 = {0.f, 0.f, 0.f, 0.f};
    f32x4 acc5[5][2][2];
    #pragma unroll
    for (int s = 0; s < 5; ++s)
        #pragma unroll
        for (int m = 0; m < 2; ++m)
            #pragma unroll
            for (int n = 0; n < 2; ++n) acc5[s][m][n] = zero4;

    #pragma unroll
    for (int kk = 0; kk < 2; ++kk) {
        bhalf8 a[2];
        #pragma unroll
        for (int m = 0; m < 2; ++m) {
            int p = wm * 32 + m * 16 + lr;
            int g = kk * 4 + lg;
            a[m] = *(const bhalf8*)((const char*)xs + p * 128 + ((g ^ (p & 7)) << 4));
        }
        #pragma unroll
        for (int s = 0; s < 5; ++s) {
            #pragma unroll
            for (int n = 0; n < 2; ++n) {
                int o = wn * 32 + n * 16 + lr;
                int g = kk * 4 + lg;
                bhalf8 b = *(const bhalf8*)((const char*)wt + s * 8192 + o * 128 + ((g ^ (o & 7)) << 4));
                #pragma unroll
                for (int m = 0; m < 2; ++m)
                    acc5[s][m][n] = __builtin_amdgcn_mfma_f32_16x16x32_bf16(a[m], b, acc5[s][m][n], 0, 0, 0);
            }
        }
    }

    #pragma unroll
    for (int m = 0; m < 2; ++m) {
        #pragma unroll
        for (int n = 0; n < 2; ++n) {
            int col = wn * 32 + n * 16 + lr;
            int pb = wm * 32 + m * 16 + lg * 4;
            #pragma unroll
            for (int r = 0; r < 4; ++r) {
                int p = pb + r;
                if (p < npts) {
                    float4 b4 = bsv[p];
                    float v = acc5[4][m][n][r]
                            + b4.x * acc5[0][m][n][r]
                            + b4.y * acc5[1][m][n][r]
                            + b4.z * acc5[2][m][n][r]
                            + b4.w * acc5[3][m][n][r];
                    v = (v + bsh[col]) * msk[p];
                    out[(long)eid[p] * 64 + col] = v;
                }
            }
        }
    }
}

extern "C" void kernel_launch(void* const* d_in, const int* in_sizes, int n_in,
                              void* d_out, int out_size, void* d_ws, size_t ws_size,
                              hipStream_t stream) {
    const float* x      = (const float*)d_in[0];  // [8,4096,64]
    const float* coord  = (const float*)d_in[1];  // [8,4096,2]
    const float* mask   = (const float*)d_in[2];  // [8,4096]
    const float* weight = (const float*)d_in[3];  // [25,64,64]
    const float* root   = (const float*)d_in[4];  // [64,64]
    const float* bias   = (const float*)d_in[5];  // [64]
    float* out = (float*)d_out;

    const int E = in_sizes[2];  // 32768

    char* ws = (char*)d_ws;
    int*    cnt2   = (int*)ws;                                 // 25*128 ints (12.8 KB)
    float4* basis4 = (float4*)(ws + 16384);                    // E float4 (512 KB)
    int*    idx2   = (int*)(ws + 16384 + (size_t)E * 16);      // 25*128*64 ints (819 KB)

    k_prep<<<NPREP, 256, 0, stream>>>(coord, basis4, cnt2, idx2, E);

    int maxTiles = (E + 63) / 64 + NCELL;   // <= 537
    k_main<<<maxTiles, 256, 0, stream>>>(x, mask, weight, root, bias, basis4, cnt2, idx2, out);
}